// Round 2
// baseline (135.970 us; speedup 1.0000x reference)
//
#include <hip/hip_runtime.h>

#define NNODES 4096
#define HID 256
#define NG 16
#define NH 8
#define HD 32
#define LN_EPS 1e-5f
// (1/sqrt(32)) * log2(e): softmax in exp2 domain (exact wrt softmax)
#define QSCALE (0.17677669529663687f * 1.4426950408889634f)
#define CAPT 384          // max padded segment length (>> 6 sigma above mean 256)
#define KLS 40            // K/Q row stride (elems): 20-dword lane stride -> 2-way banks only
#define VTS (CAPT + 2)    // V^T row stride (elements): odd-dword to spread banks
#define QSL 12            // q-tile slots per block (2 blocks x 12 covers ntj <= 24)

typedef unsigned short u16;
typedef unsigned int u32;
typedef __bf16 bf16x8 __attribute__((ext_vector_type(8)));
typedef float f32x4 __attribute__((ext_vector_type(4)));

__device__ __forceinline__ float bf2f(u16 u){
  union { u32 i; float f; } c; c.i = ((u32)u) << 16; return c.f;
}
__device__ __forceinline__ u16 f2bf(float f){
  union { float f; u32 i; } c; c.f = f;
  u32 x = c.i;
  return (u16)((x + 0x7fffu + ((x >> 16) & 1u)) >> 16);  // RNE
}

// ---------------------------------------------------------------------------
// prep: fused LN (blocks 0..1023) + weight transpose (1024..1279) + seg (1280)
__global__ __launch_bounds__(256) void prep_kernel(
    const float* __restrict__ x, const float* __restrict__ gamma,
    const float* __restrict__ beta, u16* __restrict__ h,
    const float* __restrict__ Wq, const float* __restrict__ Wk,
    const float* __restrict__ Wv, const float* __restrict__ Wo,
    u16* __restrict__ Wt, const int* __restrict__ bw, int* __restrict__ seg){
  __shared__ u16 tile[32][33];
  __shared__ int bad;
  int b = blockIdx.x;
  if (b < 1024){
    // ---- LayerNorm: 4 rows per block, one wave per row ----
    int wave = threadIdx.x >> 6, lane = threadIdx.x & 63;
    int row = b * 4 + wave;
    float4 xv = ((const float4*)x)[row * 64 + lane];
    float a0 = xv.x, a1 = xv.y, a2 = xv.z, a3 = xv.w;
    float s = a0 + a1 + a2 + a3;
    #pragma unroll
    for (int m = 1; m < 64; m <<= 1) s += __shfl_xor(s, m);
    float mu = s * (1.0f / HID);
    float d0 = a0 - mu, d1 = a1 - mu, d2 = a2 - mu, d3 = a3 - mu;
    float vv = d0*d0 + d1*d1 + d2*d2 + d3*d3;
    #pragma unroll
    for (int m = 1; m < 64; m <<= 1) vv += __shfl_xor(vv, m);
    float rs = rsqrtf(vv * (1.0f / HID) + LN_EPS);
    float4 gv = ((const float4*)gamma)[lane];
    float4 bv = ((const float4*)beta)[lane];
    ushort4 o;
    o.x = f2bf(d0 * rs * gv.x + bv.x);
    o.y = f2bf(d1 * rs * gv.y + bv.y);
    o.z = f2bf(d2 * rs * gv.z + bv.z);
    o.w = f2bf(d3 * rs * gv.w + bv.w);
    *(ushort4*)(h + (size_t)row * HID + lane * 4) = o;
  } else if (b < 1280){
    // ---- Transpose 4x 256x256 f32 weights -> bf16 Wt[n][k] = W[k][n] ----
    int idx = b - 1024;
    int w = idx >> 6;              // 64 tiles (8x8) per matrix
    int t = idx & 63;
    int bx = (t & 7) * 32, by = (t >> 3) * 32;
    const float* src = (w == 0) ? Wq : (w == 1) ? Wk : (w == 2) ? Wv : Wo;
    u16* dst = Wt + (size_t)w * HID * HID;
    int tx = threadIdx.x & 31, ty = threadIdx.x >> 5;   // 32 x 8
    #pragma unroll
    for (int r = 0; r < 32; r += 8)
      tile[ty + r][tx] = f2bf(src[(size_t)(by + ty + r) * HID + bx + tx]);
    __syncthreads();
    #pragma unroll
    for (int r = 0; r < 32; r += 8)
      dst[(size_t)(bx + ty + r) * HID + by + tx] = tile[tx][ty + r];
  } else {
    // ---- Segment boundaries; int64-vs-int32 auto-detect ----
    if (threadIdx.x == 0) bad = 0;
    __syncthreads();
    int local_bad = 0;
    for (int i = threadIdx.x; i < NNODES; i += 256){
      int v = bw[i];
      if (v < 0 || v > 15) local_bad = 1;
      if (i + 1 < NNODES && bw[i + 1] < v) local_bad = 1;
    }
    if (local_bad) atomicOr(&bad, 1);
    __syncthreads();
    int stride = bad ? 2 : 1;  // bad => actually int64
    int g = threadIdx.x;
    if (g <= NG){
      int lo = 0, hi = NNODES;
      while (lo < hi){
        int mid = (lo + hi) >> 1;
        if (bw[mid * stride] < g) lo = mid + 1; else hi = mid;
      }
      seg[g] = lo;
    }
  }
}

// ---------------------------------------------------------------------------
// GEMM: C[m][n] = A[m][k] * Bt[n][k]^T + bias (+resid). Wave = 64m x 16n.
// mfma_f32_16x16x32_bf16: A-frag lane holds A[m=lane&15][k=(lane>>4)*8+j];
// B-frag lane holds B[k=(lane>>4)*8+j][n=lane&15];
// C/D: col=lane&15, row=(lane>>4)*4+reg (m89-verified).
template<bool FINAL>
__device__ __forceinline__ void gemm_tile(const u16* __restrict__ A, const u16* __restrict__ Bt,
    const float* __restrict__ bias, const float* __restrict__ resid, void* __restrict__ out){
  int gw = blockIdx.x * 4 + (threadIdx.x >> 6);
  int lane = threadIdx.x & 63;
  int lr = lane & 15, lq = lane >> 4;
  int m0 = (gw >> 4) * 64;
  int n0 = (gw & 15) * 16;
  f32x4 acc[4] = {};
  const u16* arow = A + (size_t)(m0 + lr) * HID + lq * 8;
  const u16* brow = Bt + (size_t)(n0 + lr) * HID + lq * 8;
  #pragma unroll
  for (int k0 = 0; k0 < HID; k0 += 32){
    bf16x8 b = *(const bf16x8*)(brow + k0);
    #pragma unroll
    for (int t = 0; t < 4; t++){
      bf16x8 a = *(const bf16x8*)(arow + (size_t)t * 16 * HID + k0);
      acc[t] = __builtin_amdgcn_mfma_f32_16x16x32_bf16(a, b, acc[t], 0, 0, 0);
    }
  }
  int col = n0 + lr;
  float bb = bias[col];
  #pragma unroll
  for (int t = 0; t < 4; t++){
    #pragma unroll
    for (int r = 0; r < 4; r++){
      int row = m0 + 16 * t + lq * 4 + r;
      float val = acc[t][r] + bb;
      if (FINAL){
        val += resid[(size_t)row * HID + col];
        ((float*)out)[(size_t)row * HID + col] = val;
      } else {
        ((u16*)out)[(size_t)row * HID + col] = f2bf(val);
      }
    }
  }
}

__global__ __launch_bounds__(256) void gemm_proj_kernel(const u16* __restrict__ ao,
    const u16* __restrict__ WtO, const float* __restrict__ bo, const float* __restrict__ x,
    float* __restrict__ out){
  gemm_tile<true>(ao, WtO, bo, x, out);
}

// ---------------------------------------------------------------------------
// Fused QKV-GEMM + MFMA flash attention. One block per (q-parity, graph, head):
// grid (2, 128), 512 threads, 2 blocks/CU (70.8 KB LDS), 4 waves/SIMD.
// Phase 1: waves compute K,V for j-tiles (round-robin t%8) and Q for this
// block's parity of q-tiles, MFMA-ing h (bf16, global) against Wt slices
// (global, L1/L2-hot) exactly like gemm_tile; outputs land directly in the
// attention LDS layouts: kl[j][d] (stride 40), vt[d][j] (stride VTS, packed
// u32 stores since C-layout rows are consecutive j), ql[q][d] (stride 40).
// Q/K/V numerics are bit-identical to the old global-qkv path (same MFMA
// k-order, same f2bf(acc+bias)).
// Phase 2: one barrier, then the proven online-softmax loop; each wave owns
// one q-tile (slot s -> tile 2s+bid) and runs the FULL j-range (no split or
// merge; 4 waves/SIMD hide the serial chain). Rows j >= len hold garbage
// (finite) K/V computed from neighboring h rows -> masked by the s<len
// select; rows q >= len masked at the store.
__global__ __launch_bounds__(512, 4) void qkv_attn_kernel(
    const u16* __restrict__ h, const u16* __restrict__ Wt,
    const float* __restrict__ bq, const float* __restrict__ bk,
    const float* __restrict__ bv, const int* __restrict__ seg,
    u16* __restrict__ out){
  __shared__ u16 kl[CAPT * KLS];        // K  [j][d], padded stride
  __shared__ u16 vt[HD * VTS];          // V^T [d][j]
  __shared__ u16 ql[QSL * 16 * KLS];    // Q  [slot*16+q][d], padded stride
  int gh = blockIdx.y;
  int g = gh >> 3, hd = gh & 7;
  int bid = blockIdx.x;                 // q-tile parity (0/1)
  int start = seg[g], end = seg[g + 1];
  int len = end - start;
  if (len <= 0) return;                 // block-uniform
  if (len > CAPT) len = CAPT;           // unreachable for this input distribution
  int ntj = (len + 15) >> 4;            // 16-row j-tiles (== q-tiles), <= 24
  int wave = threadIdx.x >> 6, lane = threadIdx.x & 63;
  int lq = lane >> 4, lr = lane & 15;

  // weight rows (B-frag: lane reads Bt[n][k] row n = head base + nf*16 + lr)
  const u16* wq0p = Wt + (size_t)(hd * HD + lr) * HID;
  const u16* wk0p = wq0p + (size_t)HID * HID;
  const u16* wv0p = wq0p + (size_t)2 * HID * HID;
  float bq0 = bq[hd * HD + lr],      bq1 = bq[hd * HD + 16 + lr];
  float bk0 = bk[hd * HD + lr],      bk1 = bk[hd * HD + 16 + lr];
  float bv0 = bv[hd * HD + lr],      bv1 = bv[hd * HD + 16 + lr];

  // ---- Phase 1a: K,V j-tiles (A-frag shared between K and V: 5 ld / 4 mfma)
  for (int t = wave; t < ntj; t += 8){
    f32x4 ak0 = {}, ak1 = {}, av0 = {}, av1 = {};
    int row = start + (t << 4) + lr;
    if (row >= NNODES) row = NNODES - 1;          // clamp: garbage rows masked later
    const u16* hrow = h + (size_t)row * HID + lq * 8;
    #pragma unroll 2
    for (int k0 = 0; k0 < HID; k0 += 32){
      bf16x8 a    = *(const bf16x8*)(hrow + k0);
      bf16x8 wk0f = *(const bf16x8*)(wk0p + k0 + lq * 8);
      bf16x8 wk1f = *(const bf16x8*)(wk0p + 16 * HID + k0 + lq * 8);
      bf16x8 wv0f = *(const bf16x8*)(wv0p + k0 + lq * 8);
      bf16x8 wv1f = *(const bf16x8*)(wv0p + 16 * HID + k0 + lq * 8);
      ak0 = __builtin_amdgcn_mfma_f32_16x16x32_bf16(a, wk0f, ak0, 0, 0, 0);
      ak1 = __builtin_amdgcn_mfma_f32_16x16x32_bf16(a, wk1f, ak1, 0, 0, 0);
      av0 = __builtin_amdgcn_mfma_f32_16x16x32_bf16(a, wv0f, av0, 0, 0, 0);
      av1 = __builtin_amdgcn_mfma_f32_16x16x32_bf16(a, wv1f, av1, 0, 0, 0);
    }
    // C-layout: col d = lr (+nf*16), row j (in tile) = lq*4 + r
    int jr = (t << 4) + lq * 4;
    #pragma unroll
    for (int r = 0; r < 4; r++){
      kl[(jr + r) * KLS + lr]      = f2bf(ak0[r] + bk0);
      kl[(jr + r) * KLS + 16 + lr] = f2bf(ak1[r] + bk1);
    }
    // vt rows are d -> consecutive r are consecutive j: packable u32 stores
    *(u32*)&vt[lr * VTS + jr]            = (u32)f2bf(av0[0] + bv0) | ((u32)f2bf(av0[1] + bv0) << 16);
    *(u32*)&vt[lr * VTS + jr + 2]        = (u32)f2bf(av0[2] + bv0) | ((u32)f2bf(av0[3] + bv0) << 16);
    *(u32*)&vt[(16 + lr) * VTS + jr]     = (u32)f2bf(av1[0] + bv1) | ((u32)f2bf(av1[1] + bv1) << 16);
    *(u32*)&vt[(16 + lr) * VTS + jr + 2] = (u32)f2bf(av1[2] + bv1) | ((u32)f2bf(av1[3] + bv1) << 16);
  }

  // ---- Phase 1b: Q for this block's q-tiles (slot s -> tile 2s+bid)
  for (int s = wave; s < QSL; s += 8){
    int t = (s << 1) + bid;
    if (t >= ntj) continue;
    f32x4 aq0 = {}, aq1 = {};
    int row = start + (t << 4) + lr;
    if (row >= NNODES) row = NNODES - 1;
    const u16* hrow = h + (size_t)row * HID + lq * 8;
    #pragma unroll 2
    for (int k0 = 0; k0 < HID; k0 += 32){
      bf16x8 a    = *(const bf16x8*)(hrow + k0);
      bf16x8 wq0f = *(const bf16x8*)(wq0p + k0 + lq * 8);
      bf16x8 wq1f = *(const bf16x8*)(wq0p + 16 * HID + k0 + lq * 8);
      aq0 = __builtin_amdgcn_mfma_f32_16x16x32_bf16(a, wq0f, aq0, 0, 0, 0);
      aq1 = __builtin_amdgcn_mfma_f32_16x16x32_bf16(a, wq1f, aq1, 0, 0, 0);
    }
    int qr = (s << 4) + lq * 4;
    #pragma unroll
    for (int r = 0; r < 4; r++){
      ql[(qr + r) * KLS + lr]      = f2bf(aq0[r] + bq0);
      ql[(qr + r) * KLS + 16 + lr] = f2bf(aq1[r] + bq1);
    }
  }
  __syncthreads();

  // ---- Phase 2: online-softmax flash attention (full j-range per wave)
  for (int s = wave; s < QSL; s += 8){
    int t = (s << 1) + bid;
    if (t >= ntj) continue;
    int q0 = t << 4;
    bf16x8 qf = *(const bf16x8*)&ql[((s << 4) + lr) * KLS + lq * 8];
    float m = -3.0e38f, l = 0.f;
    f32x4 o0 = {0.f,0.f,0.f,0.f}, o1 = {0.f,0.f,0.f,0.f};
    for (int jt = 0; jt < ntj; jt++){
      int j0 = jt << 4;
      bf16x8 kf = *(const bf16x8*)&kl[(j0 + lr) * KLS + lq * 8];
      f32x4 st = __builtin_amdgcn_mfma_f32_16x16x32_bf16(kf, qf,
                   (f32x4){0.f,0.f,0.f,0.f}, 0, 0, 0);
      int jb = j0 + lq * 4;
      float s0 = (jb + 0 < len) ? st[0] * QSCALE : -3.0e38f;
      float s1 = (jb + 1 < len) ? st[1] * QSCALE : -3.0e38f;
      float s2 = (jb + 2 < len) ? st[2] * QSCALE : -3.0e38f;
      float s3 = (jb + 3 < len) ? st[3] * QSCALE : -3.0e38f;
      float tm = fmaxf(fmaxf(s0, s1), fmaxf(s2, s3));
      tm = fmaxf(tm, __shfl_xor(tm, 16));
      tm = fmaxf(tm, __shfl_xor(tm, 32));
      float mn = fmaxf(m, tm);
      float alpha = exp2f(m - mn);       // first tile: exp2(-huge) = 0
      float p0 = exp2f(s0 - mn), p1 = exp2f(s1 - mn);
      float p2 = exp2f(s2 - mn), p3 = exp2f(s3 - mn);
      float ps = (p0 + p1) + (p2 + p3);
      ps += __shfl_xor(ps, 16);
      ps += __shfl_xor(ps, 32);
      l = l * alpha + ps;
      m = mn;
      union { bf16x8 v8; u32 w[4]; } pf, vf0, vf1;
      pf.w[0] = (u32)f2bf(p0) | ((u32)f2bf(p1) << 16);
      pf.w[1] = (u32)f2bf(p2) | ((u32)f2bf(p3) << 16);
      pf.w[2] = 0; pf.w[3] = 0;
      const u16* vp0 = &vt[lr * VTS + j0 + lq * 4];
      const u16* vp1 = &vt[(16 + lr) * VTS + j0 + lq * 4];
      vf0.w[0] = *(const u32*)vp0; vf0.w[1] = *(const u32*)(vp0 + 2);
      vf0.w[2] = 0; vf0.w[3] = 0;
      vf1.w[0] = *(const u32*)vp1; vf1.w[1] = *(const u32*)(vp1 + 2);
      vf1.w[2] = 0; vf1.w[3] = 0;
      o0 = o0 * alpha;
      o1 = o1 * alpha;
      o0 = __builtin_amdgcn_mfma_f32_16x16x32_bf16(vf0.v8, pf.v8, o0, 0, 0, 0);
      o1 = __builtin_amdgcn_mfma_f32_16x16x32_bf16(vf1.v8, pf.v8, o1, 0, 0, 0);
    }
    if (q0 + lr < len){
      float rl = 1.0f / l;               // l >= 1 (own max contributes 1)
      u16* orow = out + (size_t)(start + q0 + lr) * HID + hd * HD;
      int dbase = lq * 4;
      *(u32*)&orow[dbase]          = (u32)f2bf(o0[0]*rl) | ((u32)f2bf(o0[1]*rl) << 16);
      *(u32*)&orow[dbase + 2]      = (u32)f2bf(o0[2]*rl) | ((u32)f2bf(o0[3]*rl) << 16);
      *(u32*)&orow[16 + dbase]     = (u32)f2bf(o1[0]*rl) | ((u32)f2bf(o1[1]*rl) << 16);
      *(u32*)&orow[16 + dbase + 2] = (u32)f2bf(o1[2]*rl) | ((u32)f2bf(o1[3]*rl) << 16);
    }
  }
}

// ---------------------------------------------------------------------------
// ws_size guard: paint an unmistakable sentinel if scratch is insufficient.
__global__ void sentinel_kernel(u32* __restrict__ out, int nwords){
  int i = blockIdx.x * 256 + threadIdx.x;
  if (i < nwords) out[i] = 0x46404640u;
}

// ---------------------------------------------------------------------------
extern "C" void kernel_launch(void* const* d_in, const int* in_sizes, int n_in,
                              void* d_out, int out_size, void* d_ws, size_t ws_size,
                              hipStream_t stream){
  const float* x   = (const float*)d_in[0];
  const int* batch = (const int*)d_in[1];
  const float* Wq = (const float*)d_in[2],  *bq = (const float*)d_in[3];
  const float* Wk = (const float*)d_in[4],  *bk = (const float*)d_in[5];
  const float* Wv = (const float*)d_in[6],  *bv = (const float*)d_in[7];
  const float* Wo = (const float*)d_in[8],  *bo = (const float*)d_in[9];
  const float* gamma = (const float*)d_in[10], *beta = (const float*)d_in[11];

  const size_t WT_OFF = 1024;
  const size_t AO_OFF = WT_OFF + 4 * HID * HID * 2;         // 512 KB of Wt
  const size_t BUF    = (size_t)NNODES * HID * 2;           // 2 MB (bf16)
  const size_t NEED   = AO_OFF + BUF;                       // ~2.6 MB

  if (ws_size < NEED){
    int nwords = out_size / 2;
    sentinel_kernel<<<(nwords + 255) / 256, 256, 0, stream>>>((u32*)d_out, nwords);
    return;
  }

  char* w = (char*)d_ws;
  int* seg  = (int*)(w + 128);
  u16* Wt   = (u16*)(w + WT_OFF);
  u16* ao   = (u16*)(w + AO_OFF);
  // LN output staged as bf16 in the first 2 MB of d_out (f32 out is 4 MB);
  // consumed by qkv_attn before the final f32 GEMM overwrites d_out.
  u16* h    = (u16*)d_out;

  prep_kernel<<<1281, 256, 0, stream>>>(x, gamma, beta, h, Wq, Wk, Wv, Wo, Wt, batch, seg);
  qkv_attn_kernel<<<dim3(2, NG * NH), 512, 0, stream>>>(h, Wt, bq, bk, bv, seg, ao);
  gemm_proj_kernel<<<256, 256, 0, stream>>>(ao, Wt + 3 * (size_t)HID * HID, bo, x, (float*)d_out);
}